// Round 1
// baseline (2411.561 us; speedup 1.0000x reference)
//
#include <hip/hip_runtime.h>
#include <math.h>

#define NN 131072
#define NE 2097152
#define NG 16384

__device__ __forceinline__ float lrelu(float x, float s) { return x > 0.f ? x : s * x; }

// ---------------- CSR build ----------------
__global__ void k_hist(const int* __restrict__ dst, int* __restrict__ cnt) {
    int e = blockIdx.x * 256 + threadIdx.x;
    if (e < NE) atomicAdd(&cnt[dst[e]], 1);
}

__global__ void k_scan1(const int* __restrict__ cnt, int* __restrict__ rowptr, int* __restrict__ part) {
    __shared__ int s[256];
    int t = threadIdx.x;
    int i = blockIdx.x * 256 + t;
    int v = cnt[i];
    s[t] = v;
    __syncthreads();
    for (int off = 1; off < 256; off <<= 1) {
        int x = (t >= off) ? s[t - off] : 0;
        __syncthreads();
        s[t] += x;
        __syncthreads();
    }
    rowptr[i] = s[t] - v;  // exclusive
    if (t == 255) part[blockIdx.x] = s[255];
}

__global__ void k_scan2(int* part) {
    __shared__ int s[512];
    int t = threadIdx.x;
    int v = part[t];
    s[t] = v;
    __syncthreads();
    for (int off = 1; off < 512; off <<= 1) {
        int x = (t >= off) ? s[t - off] : 0;
        __syncthreads();
        s[t] += x;
        __syncthreads();
    }
    part[t] = s[t] - v;  // exclusive
}

__global__ void k_scan3(int* __restrict__ rowptr, const int* __restrict__ part, int* __restrict__ cursor) {
    int t = threadIdx.x;
    int i = blockIdx.x * 256 + t;
    int v = rowptr[i] + part[blockIdx.x];
    rowptr[i] = v;
    cursor[i] = v;
    if (i == 0) rowptr[NN] = NE;
}

__global__ void k_scatter(const int* __restrict__ dst, int* __restrict__ cursor, int* __restrict__ perm) {
    int e = blockIdx.x * 256 + threadIdx.x;
    if (e < NE) {
        int p = atomicAdd(&cursor[dst[e]], 1);
        perm[p] = e;
    }
}

// ---------------- node transform: h = in @ W ----------------
template <int FIN, int F, int FP>
__global__ void k_transform(const float* __restrict__ in, const float* __restrict__ W, float* __restrict__ h) {
    constexpr int BN = 256 / FP;
    __shared__ float Wl[FIN * F];
    __shared__ float xl[BN * FIN];
    int t = threadIdx.x;
    for (int i = t; i < FIN * F; i += 256) Wl[i] = W[i];
    int nb = blockIdx.x * BN;
    for (int i = t; i < BN * FIN; i += 256) xl[i] = in[nb * FIN + i];
    __syncthreads();
    int nl = t / FP, f = t % FP;
    if (f < F) {
        float acc = 0.f;
#pragma unroll
        for (int k = 0; k < FIN; k++) acc += xl[nl * FIN + k] * Wl[k * F + f];
        h[(nb + nl) * F + f] = acc;
    }
}

// ---------------- per-node alpha projections ----------------
template <int H, int C>
__global__ void k_alpha(const float* __restrict__ h, const float* __restrict__ as_, const float* __restrict__ ad_,
                        float* __restrict__ alpha_s, float* __restrict__ alpha_d) {
    int i = blockIdx.x * 256 + threadIdx.x;  // n*H + hh
    if (i >= NN * H) return;
    int n = i / H, hh = i % H;
    const float* hp = h + n * (H * C) + hh * C;
    float s = 0.f, d = 0.f;
#pragma unroll
    for (int c = 0; c < C; c++) {
        float v = hp[c];
        s += v * as_[hh * C + c];
        d += v * ad_[hh * C + c];
    }
    alpha_s[i] = s;
    alpha_d[i] = d;
}

// ---------------- per-node softmax + aggregation (1 wave / node) ----------------
template <int H, int C, bool FINAL>
__global__ __launch_bounds__(64) void k_aggregate(
    const float* __restrict__ h, const float* __restrict__ asrc, const float* __restrict__ adst,
    const int* __restrict__ rowptr, const int* __restrict__ perm,
    const int* __restrict__ srcs, const float* __restrict__ ew,
    const float* __restrict__ We, const float* __restrict__ ae, const float* __restrict__ b,
    const float* __restrict__ bn_g, const float* __restrict__ bn_b,
    const float* __restrict__ bn_rm, const float* __restrict__ bn_rv,
    const int* __restrict__ batch, float* __restrict__ out) {
    constexpr int F = H * C;
    constexpr int NF = (F + 63) / 64;
    int n = blockIdx.x;
    int lane = threadIdx.x;
    int r0 = __builtin_amdgcn_readfirstlane(rowptr[n]);
    int r1 = __builtin_amdgcn_readfirstlane(rowptr[n + 1]);

    // per-head constants: lanes h<H compute, broadcast to all
    float ce_h = 0.f, ad_h = 0.f;
    if (lane < H) {
#pragma unroll
        for (int c = 0; c < C; c++) ce_h += We[lane * C + c] * ae[lane * C + c];
        ad_h = adst[n * H + lane];
    }
    float ceA[H], adA[H];
#pragma unroll
    for (int hh = 0; hh < H; hh++) {
        ceA[hh] = __shfl(ce_h, hh);
        adA[hh] = __shfl(ad_h, hh);
    }

    // pass 1: per-head max over in-edges (lanes parallel over edges)
    float m[H];
#pragma unroll
    for (int hh = 0; hh < H; hh++) m[hh] = -1e30f;
    for (int r = r0 + lane; r < r1; r += 64) {
        int e = perm[r];
        int s = srcs[e];
        float w = ew[e];
        float av[H];
        if constexpr (H == 4) {
            float4 v4 = ((const float4*)asrc)[s];
            av[0] = v4.x; av[1] = v4.y; av[2] = v4.z; av[3] = v4.w;
        } else {
            av[0] = asrc[s];
        }
#pragma unroll
        for (int hh = 0; hh < H; hh++) {
            float a = av[hh] + adA[hh] + w * ceA[hh];
            a = lrelu(a, 0.2f);
            m[hh] = fmaxf(m[hh], a);
        }
    }
#pragma unroll
    for (int hh = 0; hh < H; hh++) {
#pragma unroll
        for (int off = 32; off >= 1; off >>= 1) m[hh] = fmaxf(m[hh], __shfl_xor(m[hh], off));
    }
    float mmax_l = m[0];
    if constexpr (H == 4) {
        if (lane == 1) mmax_l = m[1];
        else if (lane == 2) mmax_l = m[2];
        else if (lane == 3) mmax_l = m[3];
    }

    // pass 2: sequential over edges, lanes parallel over features
    float acc[NF];
#pragma unroll
    for (int i = 0; i < NF; i++) acc[i] = 0.f;
    float dsum = 0.f;
    int f0 = lane;
    int h0 = f0 / C;
    int f1 = lane + 64;
    int h1_ = f1 / C;
    for (int r = r0; r < r1; ++r) {
        int e = __builtin_amdgcn_readfirstlane(perm[r]);
        int s = __builtin_amdgcn_readfirstlane(srcs[e]);
        float w = ew[e];
        float exh = 0.f;
        if (lane < H) {
            float a = asrc[s * H + lane] + ad_h + w * ce_h;
            a = lrelu(a, 0.2f);
            exh = __expf(a - mmax_l);
            dsum += exh;
        }
        float ex0 = __shfl(exh, h0 < H ? h0 : 0);
        if (f0 < F) acc[0] += h[s * F + f0] * ex0;
        if constexpr (NF > 1) {
            float ex1 = __shfl(exh, h1_);
            acc[1] += h[s * F + f1] * ex1;
        }
    }

    // epilogue
    if (f0 < F) {
        float den0 = __shfl(dsum, h0) + 1e-16f;
        float o = acc[0] / den0 + b[f0];
        if constexpr (FINAL) {
            o = (o - bn_rm[f0]) * rsqrtf(bn_rv[f0] + 1e-5f) * bn_g[f0] + bn_b[f0];
            o = lrelu(o, 0.01f);
            atomicAdd(&out[batch[n] * F + f0], o);
        } else {
            out[n * F + f0] = lrelu(o, 0.01f);
        }
    }
    if constexpr (NF > 1) {
        float den1 = __shfl(dsum, h1_) + 1e-16f;
        float o = acc[1] / den1 + b[f1];
        out[n * F + f1] = lrelu(o, 0.01f);
    }
}

// ---------------- final MLP over graphs ----------------
__global__ void k_mlp(const float* __restrict__ gbuf,
                      const float* __restrict__ Wf1, const float* __restrict__ bf1,
                      const float* __restrict__ Wf2, const float* __restrict__ bf2,
                      const float* __restrict__ Wf3, const float* __restrict__ bf3,
                      float* __restrict__ out) {
    __shared__ float W1[1500], W2[600], W3[40], B1[30], B2[20], B3[2];
    int t = threadIdx.x;
    for (int i = t; i < 1500; i += 256) W1[i] = Wf1[i];
    for (int i = t; i < 600; i += 256) W2[i] = Wf2[i];
    for (int i = t; i < 40; i += 256) W3[i] = Wf3[i];
    if (t < 30) B1[t] = bf1[t];
    if (t < 20) B2[t] = bf2[t];
    if (t < 2) B3[t] = bf3[t];
    __syncthreads();
    int g = blockIdx.x * 256 + t;
    float gv[50];
#pragma unroll
    for (int i = 0; i < 50; i++) gv[i] = gbuf[g * 50 + i];
    float h1[30];
#pragma unroll
    for (int j = 0; j < 30; j++) {
        float a = B1[j];
#pragma unroll
        for (int i = 0; i < 50; i++) a += gv[i] * W1[i * 30 + j];
        h1[j] = lrelu(a, 0.01f);
    }
    float h2[20];
#pragma unroll
    for (int j = 0; j < 20; j++) {
        float a = B2[j];
#pragma unroll
        for (int i = 0; i < 30; i++) a += h1[i] * W2[i * 20 + j];
        h2[j] = lrelu(a, 0.01f);
    }
#pragma unroll
    for (int j = 0; j < 2; j++) {
        float a = B3[j];
#pragma unroll
        for (int i = 0; i < 20; i++) a += h2[i] * W3[i * 2 + j];
        out[g * 2 + j] = a;
    }
}

extern "C" void kernel_launch(void* const* d_in, const int* in_sizes, int n_in,
                              void* d_out, int out_size, void* d_ws, size_t ws_size,
                              hipStream_t stream) {
    const float* x = (const float*)d_in[0];
    const int* ei = (const int*)d_in[1];
    const float* ew = (const float*)d_in[2];
    const int* batch = (const int*)d_in[3];
    const float* W1 = (const float*)d_in[4];
    const float* as1 = (const float*)d_in[5];
    const float* ad1 = (const float*)d_in[6];
    const float* We1 = (const float*)d_in[7];
    const float* ae1 = (const float*)d_in[8];
    const float* b1 = (const float*)d_in[9];
    const float* W2 = (const float*)d_in[10];
    const float* as2 = (const float*)d_in[11];
    const float* ad2 = (const float*)d_in[12];
    const float* We2 = (const float*)d_in[13];
    const float* ae2 = (const float*)d_in[14];
    const float* b2 = (const float*)d_in[15];
    const float* W3 = (const float*)d_in[16];
    const float* as3 = (const float*)d_in[17];
    const float* ad3 = (const float*)d_in[18];
    const float* We3 = (const float*)d_in[19];
    const float* ae3 = (const float*)d_in[20];
    const float* b3 = (const float*)d_in[21];
    const float* W4 = (const float*)d_in[22];
    const float* as4 = (const float*)d_in[23];
    const float* ad4 = (const float*)d_in[24];
    const float* We4 = (const float*)d_in[25];
    const float* ae4 = (const float*)d_in[26];
    const float* b4 = (const float*)d_in[27];
    const float* bn_g = (const float*)d_in[28];
    const float* bn_b = (const float*)d_in[29];
    const float* bn_rm = (const float*)d_in[30];
    const float* bn_rv = (const float*)d_in[31];
    const float* Wf1 = (const float*)d_in[32];
    const float* bf1 = (const float*)d_in[33];
    const float* Wf2 = (const float*)d_in[34];
    const float* bf2 = (const float*)d_in[35];
    const float* Wf3 = (const float*)d_in[36];
    const float* bf3 = (const float*)d_in[37];
    float* out = (float*)d_out;

    const int* src = ei;
    const int* dst = ei + NE;

    // workspace layout
    char* ws = (char*)d_ws;
    float* feat = (float*)ws;                 ws += (size_t)NN * 128 * 4;  // 64 MB
    float* hbuf = (float*)ws;                 ws += (size_t)NN * 128 * 4;  // 64 MB
    float* as_buf = (float*)ws;               ws += (size_t)NN * 4 * 4;
    float* ad_buf = (float*)ws;               ws += (size_t)NN * 4 * 4;
    int* cnt = (int*)ws;                      ws += (size_t)NN * 4;
    int* rowptr = (int*)ws;                   ws += (size_t)(NN + 64) * 4;
    int* cursor = (int*)ws;                   ws += (size_t)NN * 4;
    int* perm = (int*)ws;                     ws += (size_t)NE * 4;
    int* part = (int*)ws;                     ws += 512 * 4;
    float* gbuf = (float*)ws;                 ws += (size_t)NG * 50 * 4;

    // CSR build
    hipMemsetAsync(cnt, 0, (size_t)NN * 4, stream);
    hipMemsetAsync(gbuf, 0, (size_t)NG * 50 * 4, stream);
    k_hist<<<NE / 256, 256, 0, stream>>>(dst, cnt);
    k_scan1<<<NN / 256, 256, 0, stream>>>(cnt, rowptr, part);
    k_scan2<<<1, 512, 0, stream>>>(part);
    k_scan3<<<NN / 256, 256, 0, stream>>>(rowptr, part, cursor);
    k_scatter<<<NE / 256, 256, 0, stream>>>(dst, cursor, perm);

    // layer 1: fin=6, H=4, C=16 (F=64)
    k_transform<6, 64, 64><<<NN / 4, 256, 0, stream>>>(x, W1, hbuf);
    k_alpha<4, 16><<<NN * 4 / 256, 256, 0, stream>>>(hbuf, as1, ad1, as_buf, ad_buf);
    k_aggregate<4, 16, false><<<NN, 64, 0, stream>>>(hbuf, as_buf, ad_buf, rowptr, perm, src, ew,
                                                     We1, ae1, b1, nullptr, nullptr, nullptr, nullptr,
                                                     nullptr, feat);
    // layer 2: fin=64, H=4, C=32 (F=128)
    k_transform<64, 128, 128><<<NN / 2, 256, 0, stream>>>(feat, W2, hbuf);
    k_alpha<4, 32><<<NN * 4 / 256, 256, 0, stream>>>(hbuf, as2, ad2, as_buf, ad_buf);
    k_aggregate<4, 32, false><<<NN, 64, 0, stream>>>(hbuf, as_buf, ad_buf, rowptr, perm, src, ew,
                                                     We2, ae2, b2, nullptr, nullptr, nullptr, nullptr,
                                                     nullptr, feat);
    // layer 3: fin=128, H=4, C=16 (F=64)
    k_transform<128, 64, 64><<<NN / 4, 256, 0, stream>>>(feat, W3, hbuf);
    k_alpha<4, 16><<<NN * 4 / 256, 256, 0, stream>>>(hbuf, as3, ad3, as_buf, ad_buf);
    k_aggregate<4, 16, false><<<NN, 64, 0, stream>>>(hbuf, as_buf, ad_buf, rowptr, perm, src, ew,
                                                     We3, ae3, b3, nullptr, nullptr, nullptr, nullptr,
                                                     nullptr, feat);
    // layer 4: fin=64, H=1, C=50 (F=50), fused BN+lrelu+graph pooling
    k_transform<64, 50, 64><<<NN / 4, 256, 0, stream>>>(feat, W4, hbuf);
    k_alpha<1, 50><<<NN / 256, 256, 0, stream>>>(hbuf, as4, ad4, as_buf, ad_buf);
    k_aggregate<1, 50, true><<<NN, 64, 0, stream>>>(hbuf, as_buf, ad_buf, rowptr, perm, src, ew,
                                                    We4, ae4, b4, bn_g, bn_b, bn_rm, bn_rv,
                                                    batch, gbuf);
    // final MLP
    k_mlp<<<NG / 256, 256, 0, stream>>>(gbuf, Wf1, bf1, Wf2, bf2, Wf3, bf3, out);
}

// Round 2
// 1770.691 us; speedup vs baseline: 1.3619x; 1.3619x over previous
//
#include <hip/hip_runtime.h>
#include <hip/hip_fp16.h>
#include <math.h>

#define NN 131072
#define NE 2097152
#define NG 16384

__device__ __forceinline__ float lrelu(float x, float s) { return x > 0.f ? x : s * x; }

// ---------------- CSR build ----------------
__global__ void k_hist(const int* __restrict__ dst, int* __restrict__ cnt) {
    int e = blockIdx.x * 256 + threadIdx.x;
    if (e < NE) atomicAdd(&cnt[dst[e]], 1);
}

__global__ void k_scan1(const int* __restrict__ cnt, int* __restrict__ rowptr, int* __restrict__ part) {
    __shared__ int s[256];
    int t = threadIdx.x;
    int i = blockIdx.x * 256 + t;
    int v = cnt[i];
    s[t] = v;
    __syncthreads();
    for (int off = 1; off < 256; off <<= 1) {
        int x = (t >= off) ? s[t - off] : 0;
        __syncthreads();
        s[t] += x;
        __syncthreads();
    }
    rowptr[i] = s[t] - v;  // exclusive
    if (t == 255) part[blockIdx.x] = s[255];
}

__global__ void k_scan2(int* part) {
    __shared__ int s[512];
    int t = threadIdx.x;
    int v = part[t];
    s[t] = v;
    __syncthreads();
    for (int off = 1; off < 512; off <<= 1) {
        int x = (t >= off) ? s[t - off] : 0;
        __syncthreads();
        s[t] += x;
        __syncthreads();
    }
    part[t] = s[t] - v;  // exclusive
}

__global__ void k_scan3(int* __restrict__ rowptr, const int* __restrict__ part, int* __restrict__ cursor) {
    int t = threadIdx.x;
    int i = blockIdx.x * 256 + t;
    int v = rowptr[i] + part[blockIdx.x];
    rowptr[i] = v;
    cursor[i] = v;
    if (i == 0) rowptr[NN] = NE;
}

__global__ void k_scatter(const int* __restrict__ dst, int* __restrict__ cursor, int* __restrict__ perm) {
    int e = blockIdx.x * 256 + threadIdx.x;
    if (e < NE) {
        int p = atomicAdd(&cursor[dst[e]], 1);
        perm[p] = e;
    }
}

// ---------------- node transform: h = in @ W  (writes fp16) ----------------
template <int FIN, int F, int FP>
__global__ void k_transform(const float* __restrict__ in, const float* __restrict__ W, __half* __restrict__ h) {
    constexpr int BN = 256 / FP;
    __shared__ float Wl[FIN * F];
    __shared__ float xl[BN * FIN];
    int t = threadIdx.x;
    for (int i = t; i < FIN * F; i += 256) Wl[i] = W[i];
    int nb = blockIdx.x * BN;
    for (int i = t; i < BN * FIN; i += 256) xl[i] = in[nb * FIN + i];
    __syncthreads();
    int nl = t / FP, f = t % FP;
    if (f < F) {
        float acc = 0.f;
#pragma unroll
        for (int k = 0; k < FIN; k++) acc += xl[nl * FIN + k] * Wl[k * F + f];
        h[(size_t)(nb + nl) * F + f] = __float2half(acc);
    }
}

// ---------------- per-node alpha projections (reads fp16 h) ----------------
template <int H, int C>
__global__ void k_alpha(const __half* __restrict__ h, const float* __restrict__ as_, const float* __restrict__ ad_,
                        float* __restrict__ alpha_s, float* __restrict__ alpha_d) {
    int i = blockIdx.x * 256 + threadIdx.x;  // n*H + hh
    if (i >= NN * H) return;
    int n = i / H, hh = i % H;
    const __half* hp = h + (size_t)n * (H * C) + hh * C;
    float s = 0.f, d = 0.f;
#pragma unroll
    for (int c = 0; c < C; c++) {
        float v = __half2float(hp[c]);
        s += v * as_[hh * C + c];
        d += v * ad_[hh * C + c];
    }
    alpha_s[i] = s;
    alpha_d[i] = d;
}

// ---------------- per-node softmax + aggregation (1 wave / node) ----------------
// Edge-parallel alpha/max/exp/denom (one edge per lane, deg<=64 fast path),
// then feature-parallel accumulate with LDS-staged (src, ex) metadata.
template <int H, int C, bool FINAL>
__global__ __launch_bounds__(64) void k_aggregate(
    const __half* __restrict__ h, const float* __restrict__ asrc, const float* __restrict__ adst,
    const int* __restrict__ rowptr, const int* __restrict__ perm,
    const int* __restrict__ srcs, const float* __restrict__ ew,
    const float* __restrict__ We, const float* __restrict__ ae, const float* __restrict__ b,
    const float* __restrict__ bn_g, const float* __restrict__ bn_b,
    const float* __restrict__ bn_rm, const float* __restrict__ bn_rv,
    const int* __restrict__ batch, float* __restrict__ out) {
    constexpr int F = H * C;
    constexpr bool PACK2 = (F > 64);
    constexpr int CL = PACK2 ? (C / 2) : C;  // lanes per head group
    __shared__ float lds_ex[64 * H];
    __shared__ int lds_s[64];

    int n = blockIdx.x;
    int lane = threadIdx.x;
    int r0 = __builtin_amdgcn_readfirstlane(rowptr[n]);
    int r1 = __builtin_amdgcn_readfirstlane(rowptr[n + 1]);
    int deg = r1 - r0;

    // per-head constants (uniform -> scalar loads)
    float ce[H], ad[H];
#pragma unroll
    for (int hh = 0; hh < H; hh++) {
        float c = 0.f;
#pragma unroll
        for (int cc = 0; cc < C; cc++) c += We[hh * C + cc] * ae[hh * C + cc];
        ce[hh] = c;
        ad[hh] = adst[n * H + hh];
    }

    // ---- edge-parallel: one edge per lane ----
    bool val = lane < deg;
    int s_l = 0;
    float w_l = 0.f;
    if (val) {
        int e = perm[r0 + lane];
        s_l = srcs[e];
        w_l = ew[e];
    }
    float a_l[H];
#pragma unroll
    for (int hh = 0; hh < H; hh++) a_l[hh] = -1e30f;
    if (val) {
#pragma unroll
        for (int hh = 0; hh < H; hh++)
            a_l[hh] = lrelu(asrc[s_l * H + hh] + ad[hh] + w_l * ce[hh], 0.2f);
    }

    // max (include overflow edges, rare)
    float m[H];
#pragma unroll
    for (int hh = 0; hh < H; hh++) m[hh] = a_l[hh];
    for (int r = r0 + 64 + lane; r < r1; r += 64) {
        int e = perm[r];
        int s = srcs[e];
        float w = ew[e];
#pragma unroll
        for (int hh = 0; hh < H; hh++)
            m[hh] = fmaxf(m[hh], lrelu(asrc[s * H + hh] + ad[hh] + w * ce[hh], 0.2f));
    }
#pragma unroll
    for (int hh = 0; hh < H; hh++) {
#pragma unroll
        for (int off = 32; off >= 1; off >>= 1) m[hh] = fmaxf(m[hh], __shfl_xor(m[hh], off));
    }

    // exp + denom
    float ex_l[H], psum[H];
#pragma unroll
    for (int hh = 0; hh < H; hh++) {
        ex_l[hh] = val ? __expf(a_l[hh] - m[hh]) : 0.f;
        psum[hh] = ex_l[hh];
    }
    for (int r = r0 + 64 + lane; r < r1; r += 64) {
        int e = perm[r];
        int s = srcs[e];
        float w = ew[e];
#pragma unroll
        for (int hh = 0; hh < H; hh++)
            psum[hh] += __expf(lrelu(asrc[s * H + hh] + ad[hh] + w * ce[hh], 0.2f) - m[hh]);
    }
    float den[H];
#pragma unroll
    for (int hh = 0; hh < H; hh++) {
        float v = psum[hh];
#pragma unroll
        for (int off = 32; off >= 1; off >>= 1) v += __shfl_xor(v, off);
        den[hh] = v + 1e-16f;
    }

    // stage (src, ex) in LDS
    lds_s[lane] = s_l;
#pragma unroll
    for (int hh = 0; hh < H; hh++) lds_ex[lane * H + hh] = ex_l[hh];
    __syncthreads();

    // per-lane head select
    int hsel = (H == 1) ? 0 : (lane / CL);
    float densel, msel;
    if constexpr (H == 1) {
        densel = den[0];
        msel = m[0];
    } else {
        densel = hsel == 0 ? den[0] : hsel == 1 ? den[1] : hsel == 2 ? den[2] : den[3];
        msel = hsel == 0 ? m[0] : hsel == 1 ? m[1] : hsel == 2 ? m[2] : m[3];
    }
    float rden = 1.f / densel;

    int jn = deg < 64 ? deg : 64;

    if constexpr (PACK2) {
        // F=128: each lane covers features 2*lane, 2*lane+1 (same head)
        float accx = 0.f, accy = 0.f;
        const uint* h2 = (const uint*)h;
#pragma unroll 4
        for (int j = 0; j < jn; ++j) {
            int s = __builtin_amdgcn_readfirstlane(lds_s[j]);
            float exj = lds_ex[j * H + hsel];
            uint p = h2[(size_t)s * (F / 2) + lane];
            __half2 hp = *(__half2*)&p;
            accx += __low2float(hp) * exj;
            accy += __high2float(hp) * exj;
        }
        // overflow edges (rare): sequential
        for (int r = r0 + 64; r < r1; ++r) {
            int e = __builtin_amdgcn_readfirstlane(perm[r]);
            int s = __builtin_amdgcn_readfirstlane(srcs[e]);
            float w = ew[e];
            float exA[H];
#pragma unroll
            for (int hh = 0; hh < H; hh++)
                exA[hh] = __expf(lrelu(asrc[s * H + hh] + ad[hh] + w * ce[hh], 0.2f) - m[hh]);
            float exj = hsel == 0 ? exA[0] : hsel == 1 ? exA[1] : hsel == 2 ? exA[2] : exA[3];
            uint p = h2[(size_t)s * (F / 2) + lane];
            __half2 hp = *(__half2*)&p;
            accx += __low2float(hp) * exj;
            accy += __high2float(hp) * exj;
        }
        int f0 = 2 * lane;
        float o0 = lrelu(accx * rden + b[f0], 0.01f);
        float o1 = lrelu(accy * rden + b[f0 + 1], 0.01f);
        ((float2*)out)[(size_t)n * (F / 2) + lane] = make_float2(o0, o1);
    } else {
        float acc = 0.f;
#pragma unroll 4
        for (int j = 0; j < jn; ++j) {
            int s = __builtin_amdgcn_readfirstlane(lds_s[j]);
            float exj = lds_ex[j * H + hsel];
            float hv = (lane < F) ? __half2float(h[(size_t)s * F + lane]) : 0.f;
            acc += hv * exj;
        }
        for (int r = r0 + 64; r < r1; ++r) {
            int e = __builtin_amdgcn_readfirstlane(perm[r]);
            int s = __builtin_amdgcn_readfirstlane(srcs[e]);
            float w = ew[e];
            float exA[H];
#pragma unroll
            for (int hh = 0; hh < H; hh++)
                exA[hh] = __expf(lrelu(asrc[s * H + hh] + ad[hh] + w * ce[hh], 0.2f) - m[hh]);
            float exj;
            if constexpr (H == 1) exj = exA[0];
            else exj = hsel == 0 ? exA[0] : hsel == 1 ? exA[1] : hsel == 2 ? exA[2] : exA[3];
            float hv = (lane < F) ? __half2float(h[(size_t)s * F + lane]) : 0.f;
            acc += hv * exj;
        }
        if (lane < F) {
            float o = acc * rden + b[lane];
            if constexpr (FINAL) {
                o = (o - bn_rm[lane]) * rsqrtf(bn_rv[lane] + 1e-5f) * bn_g[lane] + bn_b[lane];
                o = lrelu(o, 0.01f);
                int g = __builtin_amdgcn_readfirstlane(batch[n]);
                atomicAdd(&out[(size_t)g * F + lane], o);
            } else {
                out[(size_t)n * F + lane] = lrelu(o, 0.01f);
            }
        }
    }
}

// ---------------- final MLP over graphs ----------------
__global__ void k_mlp(const float* __restrict__ gbuf,
                      const float* __restrict__ Wf1, const float* __restrict__ bf1,
                      const float* __restrict__ Wf2, const float* __restrict__ bf2,
                      const float* __restrict__ Wf3, const float* __restrict__ bf3,
                      float* __restrict__ out) {
    __shared__ float W1[1500], W2[600], W3[40], B1[30], B2[20], B3[2];
    int t = threadIdx.x;
    for (int i = t; i < 1500; i += 256) W1[i] = Wf1[i];
    for (int i = t; i < 600; i += 256) W2[i] = Wf2[i];
    for (int i = t; i < 40; i += 256) W3[i] = Wf3[i];
    if (t < 30) B1[t] = bf1[t];
    if (t < 20) B2[t] = bf2[t];
    if (t < 2) B3[t] = bf3[t];
    __syncthreads();
    int g = blockIdx.x * 256 + t;
    float gv[50];
#pragma unroll
    for (int i = 0; i < 50; i++) gv[i] = gbuf[g * 50 + i];
    float h1[30];
#pragma unroll
    for (int j = 0; j < 30; j++) {
        float a = B1[j];
#pragma unroll
        for (int i = 0; i < 50; i++) a += gv[i] * W1[i * 30 + j];
        h1[j] = lrelu(a, 0.01f);
    }
    float h2[20];
#pragma unroll
    for (int j = 0; j < 20; j++) {
        float a = B2[j];
#pragma unroll
        for (int i = 0; i < 30; i++) a += h1[i] * W2[i * 20 + j];
        h2[j] = lrelu(a, 0.01f);
    }
#pragma unroll
    for (int j = 0; j < 2; j++) {
        float a = B3[j];
#pragma unroll
        for (int i = 0; i < 20; i++) a += h2[i] * W3[i * 2 + j];
        out[g * 2 + j] = a;
    }
}

extern "C" void kernel_launch(void* const* d_in, const int* in_sizes, int n_in,
                              void* d_out, int out_size, void* d_ws, size_t ws_size,
                              hipStream_t stream) {
    const float* x = (const float*)d_in[0];
    const int* ei = (const int*)d_in[1];
    const float* ew = (const float*)d_in[2];
    const int* batch = (const int*)d_in[3];
    const float* W1 = (const float*)d_in[4];
    const float* as1 = (const float*)d_in[5];
    const float* ad1 = (const float*)d_in[6];
    const float* We1 = (const float*)d_in[7];
    const float* ae1 = (const float*)d_in[8];
    const float* b1 = (const float*)d_in[9];
    const float* W2 = (const float*)d_in[10];
    const float* as2 = (const float*)d_in[11];
    const float* ad2 = (const float*)d_in[12];
    const float* We2 = (const float*)d_in[13];
    const float* ae2 = (const float*)d_in[14];
    const float* b2 = (const float*)d_in[15];
    const float* W3 = (const float*)d_in[16];
    const float* as3 = (const float*)d_in[17];
    const float* ad3 = (const float*)d_in[18];
    const float* We3 = (const float*)d_in[19];
    const float* ae3 = (const float*)d_in[20];
    const float* b3 = (const float*)d_in[21];
    const float* W4 = (const float*)d_in[22];
    const float* as4 = (const float*)d_in[23];
    const float* ad4 = (const float*)d_in[24];
    const float* We4 = (const float*)d_in[25];
    const float* ae4 = (const float*)d_in[26];
    const float* b4 = (const float*)d_in[27];
    const float* bn_g = (const float*)d_in[28];
    const float* bn_b = (const float*)d_in[29];
    const float* bn_rm = (const float*)d_in[30];
    const float* bn_rv = (const float*)d_in[31];
    const float* Wf1 = (const float*)d_in[32];
    const float* bf1 = (const float*)d_in[33];
    const float* Wf2 = (const float*)d_in[34];
    const float* bf2 = (const float*)d_in[35];
    const float* Wf3 = (const float*)d_in[36];
    const float* bf3 = (const float*)d_in[37];
    float* out = (float*)d_out;

    const int* src = ei;
    const int* dst = ei + NE;

    // workspace layout
    char* ws = (char*)d_ws;
    float* feat = (float*)ws;   ws += (size_t)NN * 128 * 4;  // 64 MB (f32 layer activations)
    __half* hbuf = (__half*)ws; ws += (size_t)NN * 128 * 2;  // 32 MB (fp16 transformed h)
    float* as_buf = (float*)ws; ws += (size_t)NN * 4 * 4;
    float* ad_buf = (float*)ws; ws += (size_t)NN * 4 * 4;
    int* cnt = (int*)ws;        ws += (size_t)NN * 4;
    int* rowptr = (int*)ws;     ws += (size_t)(NN + 64) * 4;
    int* cursor = (int*)ws;     ws += (size_t)NN * 4;
    int* perm = (int*)ws;       ws += (size_t)NE * 4;
    int* part = (int*)ws;       ws += 512 * 4;
    float* gbuf = (float*)ws;   ws += (size_t)NG * 50 * 4;

    // CSR build
    hipMemsetAsync(cnt, 0, (size_t)NN * 4, stream);
    hipMemsetAsync(gbuf, 0, (size_t)NG * 50 * 4, stream);
    k_hist<<<NE / 256, 256, 0, stream>>>(dst, cnt);
    k_scan1<<<NN / 256, 256, 0, stream>>>(cnt, rowptr, part);
    k_scan2<<<1, 512, 0, stream>>>(part);
    k_scan3<<<NN / 256, 256, 0, stream>>>(rowptr, part, cursor);
    k_scatter<<<NE / 256, 256, 0, stream>>>(dst, cursor, perm);

    // layer 1: fin=6, H=4, C=16 (F=64)
    k_transform<6, 64, 64><<<NN / 4, 256, 0, stream>>>(x, W1, hbuf);
    k_alpha<4, 16><<<NN * 4 / 256, 256, 0, stream>>>(hbuf, as1, ad1, as_buf, ad_buf);
    k_aggregate<4, 16, false><<<NN, 64, 0, stream>>>(hbuf, as_buf, ad_buf, rowptr, perm, src, ew,
                                                     We1, ae1, b1, nullptr, nullptr, nullptr, nullptr,
                                                     nullptr, feat);
    // layer 2: fin=64, H=4, C=32 (F=128)
    k_transform<64, 128, 128><<<NN / 2, 256, 0, stream>>>(feat, W2, hbuf);
    k_alpha<4, 32><<<NN * 4 / 256, 256, 0, stream>>>(hbuf, as2, ad2, as_buf, ad_buf);
    k_aggregate<4, 32, false><<<NN, 64, 0, stream>>>(hbuf, as_buf, ad_buf, rowptr, perm, src, ew,
                                                     We2, ae2, b2, nullptr, nullptr, nullptr, nullptr,
                                                     nullptr, feat);
    // layer 3: fin=128, H=4, C=16 (F=64)
    k_transform<128, 64, 64><<<NN / 4, 256, 0, stream>>>(feat, W3, hbuf);
    k_alpha<4, 16><<<NN * 4 / 256, 256, 0, stream>>>(hbuf, as3, ad3, as_buf, ad_buf);
    k_aggregate<4, 16, false><<<NN, 64, 0, stream>>>(hbuf, as_buf, ad_buf, rowptr, perm, src, ew,
                                                     We3, ae3, b3, nullptr, nullptr, nullptr, nullptr,
                                                     nullptr, feat);
    // layer 4: fin=64, H=1, C=50 (F=50), fused BN+lrelu+graph pooling
    k_transform<64, 50, 64><<<NN / 4, 256, 0, stream>>>(feat, W4, hbuf);
    k_alpha<1, 50><<<NN / 256, 256, 0, stream>>>(hbuf, as4, ad4, as_buf, ad_buf);
    k_aggregate<1, 50, true><<<NN, 64, 0, stream>>>(hbuf, as_buf, ad_buf, rowptr, perm, src, ew,
                                                    We4, ae4, b4, bn_g, bn_b, bn_rm, bn_rv,
                                                    batch, gbuf);
    // final MLP
    k_mlp<<<NG / 256, 256, 0, stream>>>(gbuf, Wf1, bf1, Wf2, bf2, Wf3, bf3, out);
}

// Round 3
// 1599.524 us; speedup vs baseline: 1.5077x; 1.1070x over previous
//
#include <hip/hip_runtime.h>
#include <hip/hip_fp16.h>
#include <math.h>

#define NN 131072
#define NE 2097152
#define NG 16384

__device__ __forceinline__ float lrelu(float x, float s) { return x > 0.f ? x : s * x; }

template <int H>
__device__ __forceinline__ float sel_h(const float* a, int hsel) {
    if constexpr (H == 1) return a[0];
    else return hsel == 0 ? a[0] : hsel == 1 ? a[1] : hsel == 2 ? a[2] : a[3];
}

// ---------------- CSR build ----------------
__global__ void k_hist(const int* __restrict__ dst, int* __restrict__ cnt) {
    int e = blockIdx.x * 256 + threadIdx.x;
    if (e < NE) atomicAdd(&cnt[dst[e]], 1);
}

__global__ void k_scan1(const int* __restrict__ cnt, int* __restrict__ rowptr, int* __restrict__ part) {
    __shared__ int s[256];
    int t = threadIdx.x;
    int i = blockIdx.x * 256 + t;
    int v = cnt[i];
    s[t] = v;
    __syncthreads();
    for (int off = 1; off < 256; off <<= 1) {
        int x = (t >= off) ? s[t - off] : 0;
        __syncthreads();
        s[t] += x;
        __syncthreads();
    }
    rowptr[i] = s[t] - v;  // exclusive
    if (t == 255) part[blockIdx.x] = s[255];
}

__global__ void k_scan2(int* part) {
    __shared__ int s[512];
    int t = threadIdx.x;
    int v = part[t];
    s[t] = v;
    __syncthreads();
    for (int off = 1; off < 512; off <<= 1) {
        int x = (t >= off) ? s[t - off] : 0;
        __syncthreads();
        s[t] += x;
        __syncthreads();
    }
    part[t] = s[t] - v;  // exclusive
}

__global__ void k_scan3(int* __restrict__ rowptr, const int* __restrict__ part, int* __restrict__ cursor) {
    int t = threadIdx.x;
    int i = blockIdx.x * 256 + t;
    int v = rowptr[i] + part[blockIdx.x];
    rowptr[i] = v;
    cursor[i] = v;
    if (i == 0) rowptr[NN] = NE;
}

__global__ void k_scatter(const int* __restrict__ dst, int* __restrict__ cursor, int* __restrict__ perm) {
    int e = blockIdx.x * 256 + threadIdx.x;
    if (e < NE) {
        int p = atomicAdd(&cursor[dst[e]], 1);
        perm[p] = e;
    }
}

// ---------------- node transform: h = in @ W (fp16 out, optional zero-pad to FSO) ----------------
template <int FIN, int F, int FP, int FSO>
__global__ void k_transform(const float* __restrict__ in, const float* __restrict__ W, __half* __restrict__ h) {
    constexpr int BN = 256 / FP;
    __shared__ float Wl[FIN * F];
    __shared__ float xl[BN * FIN];
    int t = threadIdx.x;
    for (int i = t; i < FIN * F; i += 256) Wl[i] = W[i];
    int nb = blockIdx.x * BN;
    for (int i = t; i < BN * FIN; i += 256) xl[i] = in[(size_t)nb * FIN + i];
    __syncthreads();
    int nl = t / FP, f = t % FP;
    if (f < F) {
        float acc = 0.f;
#pragma unroll
        for (int k = 0; k < FIN; k++) acc += xl[nl * FIN + k] * Wl[k * F + f];
        h[(size_t)(nb + nl) * FSO + f] = __float2half(acc);
    } else if (f < FSO) {
        h[(size_t)(nb + nl) * FSO + f] = __float2half(0.f);
    }
}

// ---------------- per-node alpha projections ----------------
template <int H, int C, int FSO>
__global__ void k_alpha(const __half* __restrict__ h, const float* __restrict__ as_, const float* __restrict__ ad_,
                        float* __restrict__ alpha_s, float* __restrict__ alpha_d) {
    int i = blockIdx.x * 256 + threadIdx.x;  // n*H + hh
    if (i >= NN * H) return;
    int n = i / H, hh = i % H;
    const __half* hp = h + (size_t)n * FSO + hh * C;
    float s = 0.f, d = 0.f;
#pragma unroll
    for (int c = 0; c < C; c++) {
        float v = __half2float(hp[c]);
        s += v * as_[hh * C + c];
        d += v * ad_[hh * C + c];
    }
    alpha_s[i] = s;
    alpha_d[i] = d;
}

// ---------------- per-node softmax + aggregation (1 wave / node, 4 nodes / block) ----------------
template <int H, int C, int FS, bool FINAL>
__global__ __launch_bounds__(256) void k_aggregate(
    const __half* __restrict__ h, const float* __restrict__ asrc, const float* __restrict__ adst,
    const int* __restrict__ rowptr, const int* __restrict__ perm,
    const int* __restrict__ srcs, const float* __restrict__ ew,
    const float* __restrict__ We, const float* __restrict__ ae, const float* __restrict__ b,
    const float* __restrict__ bn_g, const float* __restrict__ bn_b,
    const float* __restrict__ bn_rm, const float* __restrict__ bn_rv,
    float* __restrict__ out) {
    constexpr int F = H * C;
    constexpr bool PACK2 = (F > 64);
    __shared__ float lds_ex[4][64 * H];
    __shared__ int lds_s[4][64];

    int wid = threadIdx.x >> 6;
    int lane = threadIdx.x & 63;
    int n = blockIdx.x * 4 + wid;
    int r0 = __builtin_amdgcn_readfirstlane(rowptr[n]);
    int r1 = __builtin_amdgcn_readfirstlane(rowptr[n + 1]);
    int deg = r1 - r0;

    // per-head constants
    float ce[H], ad[H];
#pragma unroll
    for (int hh = 0; hh < H; hh++) {
        float c = 0.f;
#pragma unroll
        for (int cc = 0; cc < C; cc++) c += We[hh * C + cc] * ae[hh * C + cc];
        ce[hh] = c;
        ad[hh] = adst[(size_t)n * H + hh];
    }

    // ---- edge-parallel: one edge per lane ----
    bool val = lane < deg;
    int s_l = 0;
    float w_l = 0.f;
    if (val) {
        int e = perm[r0 + lane];
        s_l = srcs[e];
        w_l = ew[e];
    }
    float a_l[H];
#pragma unroll
    for (int hh = 0; hh < H; hh++) a_l[hh] = -1e30f;
    if (val) {
        if constexpr (H == 4) {
            float4 v4 = ((const float4*)asrc)[s_l];
            a_l[0] = lrelu(v4.x + ad[0] + w_l * ce[0], 0.2f);
            a_l[1] = lrelu(v4.y + ad[1] + w_l * ce[1], 0.2f);
            a_l[2] = lrelu(v4.z + ad[2] + w_l * ce[2], 0.2f);
            a_l[3] = lrelu(v4.w + ad[3] + w_l * ce[3], 0.2f);
        } else {
            a_l[0] = lrelu(asrc[s_l] + ad[0] + w_l * ce[0], 0.2f);
        }
    }

    // max
    float m[H];
#pragma unroll
    for (int hh = 0; hh < H; hh++) m[hh] = a_l[hh];
    for (int r = r0 + 64 + lane; r < r1; r += 64) {
        int e = perm[r];
        int s = srcs[e];
        float w = ew[e];
        if constexpr (H == 4) {
            float4 v4 = ((const float4*)asrc)[s];
            m[0] = fmaxf(m[0], lrelu(v4.x + ad[0] + w * ce[0], 0.2f));
            m[1] = fmaxf(m[1], lrelu(v4.y + ad[1] + w * ce[1], 0.2f));
            m[2] = fmaxf(m[2], lrelu(v4.z + ad[2] + w * ce[2], 0.2f));
            m[3] = fmaxf(m[3], lrelu(v4.w + ad[3] + w * ce[3], 0.2f));
        } else {
            m[0] = fmaxf(m[0], lrelu(asrc[s] + ad[0] + w * ce[0], 0.2f));
        }
    }
#pragma unroll
    for (int hh = 0; hh < H; hh++) {
#pragma unroll
        for (int off = 32; off >= 1; off >>= 1) m[hh] = fmaxf(m[hh], __shfl_xor(m[hh], off));
    }

    // exp + denom
    float ex_l[H], psum[H];
#pragma unroll
    for (int hh = 0; hh < H; hh++) {
        ex_l[hh] = val ? __expf(a_l[hh] - m[hh]) : 0.f;
        psum[hh] = ex_l[hh];
    }
    for (int r = r0 + 64 + lane; r < r1; r += 64) {
        int e = perm[r];
        int s = srcs[e];
        float w = ew[e];
        if constexpr (H == 4) {
            float4 v4 = ((const float4*)asrc)[s];
            psum[0] += __expf(lrelu(v4.x + ad[0] + w * ce[0], 0.2f) - m[0]);
            psum[1] += __expf(lrelu(v4.y + ad[1] + w * ce[1], 0.2f) - m[1]);
            psum[2] += __expf(lrelu(v4.z + ad[2] + w * ce[2], 0.2f) - m[2]);
            psum[3] += __expf(lrelu(v4.w + ad[3] + w * ce[3], 0.2f) - m[3]);
        } else {
            psum[0] += __expf(lrelu(asrc[s] + ad[0] + w * ce[0], 0.2f) - m[0]);
        }
    }
    float rden[H];
#pragma unroll
    for (int hh = 0; hh < H; hh++) {
        float v = psum[hh];
#pragma unroll
        for (int off = 32; off >= 1; off >>= 1) v += __shfl_xor(v, off);
        rden[hh] = 1.f / (v + 1e-16f);
    }

    // stage (src, att=ex/den) in LDS
    lds_s[wid][lane] = s_l;
#pragma unroll
    for (int hh = 0; hh < H; hh++) lds_ex[wid][lane * H + hh] = ex_l[hh] * rden[hh];
    __syncthreads();

    int jn = deg < 64 ? deg : 64;
    const uint* h2 = (const uint*)h;

    if constexpr (PACK2) {
        // F=128: lane covers features 2*lane, 2*lane+1; 1 edge/iter
        int hsel = lane / (C / 2);
        float accx = 0.f, accy = 0.f;
#pragma unroll 4
        for (int j = 0; j < jn; ++j) {
            int s = __builtin_amdgcn_readfirstlane(lds_s[wid][j]);
            float att = lds_ex[wid][j * H + hsel];
            uint p = h2[(size_t)s * (FS / 2) + lane];
            __half2 hp = *(__half2*)&p;
            accx += __low2float(hp) * att;
            accy += __high2float(hp) * att;
        }
        if (deg > 64) {
            float rdensel = sel_h<H>(rden, hsel);
            float msel = sel_h<H>(m, hsel);
            for (int r = r0 + 64; r < r1; ++r) {
                int e = __builtin_amdgcn_readfirstlane(perm[r]);
                int s = __builtin_amdgcn_readfirstlane(srcs[e]);
                float w = ew[e];
                float aA[H];
                float4 v4 = ((const float4*)asrc)[s];
                aA[0] = lrelu(v4.x + ad[0] + w * ce[0], 0.2f);
                aA[1] = lrelu(v4.y + ad[1] + w * ce[1], 0.2f);
                aA[2] = lrelu(v4.z + ad[2] + w * ce[2], 0.2f);
                aA[3] = lrelu(v4.w + ad[3] + w * ce[3], 0.2f);
                float att = __expf(sel_h<H>(aA, hsel) - msel) * rdensel;
                uint p = h2[(size_t)s * (FS / 2) + lane];
                __half2 hp = *(__half2*)&p;
                accx += __low2float(hp) * att;
                accy += __high2float(hp) * att;
            }
        }
        int f0 = 2 * lane;
        float o0 = lrelu(accx + b[f0], 0.01f);
        float o1 = lrelu(accy + b[f0 + 1], 0.01f);
        ((float2*)out)[(size_t)n * (F / 2) + lane] = make_float2(o0, o1);
    } else {
        // F<=64 (FS=64): two edges per iter; half-wave per edge, lane covers 2 features
        int sub = lane >> 5;
        int flane = lane & 31;
        int f0 = 2 * flane;
        int hsel = (H == 1) ? 0 : f0 / C;
        float accx = 0.f, accy = 0.f;
#pragma unroll 4
        for (int j = sub; j < jn; j += 2) {
            int s = lds_s[wid][j];
            float att = lds_ex[wid][j * H + hsel];
            uint p = h2[(size_t)s * (FS / 2) + flane];
            __half2 hp = *(__half2*)&p;
            accx += __low2float(hp) * att;
            accy += __high2float(hp) * att;
        }
        if (deg > 64) {
            float rdensel = sel_h<H>(rden, hsel);
            float msel = sel_h<H>(m, hsel);
            for (int r = r0 + 64; r < r1; ++r) {
                int e = __builtin_amdgcn_readfirstlane(perm[r]);
                int s = __builtin_amdgcn_readfirstlane(srcs[e]);
                float w = ew[e];
                float aA[H];
                if constexpr (H == 4) {
                    float4 v4 = ((const float4*)asrc)[s];
                    aA[0] = lrelu(v4.x + ad[0] + w * ce[0], 0.2f);
                    aA[1] = lrelu(v4.y + ad[1] + w * ce[1], 0.2f);
                    aA[2] = lrelu(v4.z + ad[2] + w * ce[2], 0.2f);
                    aA[3] = lrelu(v4.w + ad[3] + w * ce[3], 0.2f);
                } else {
                    aA[0] = lrelu(asrc[s] + ad[0] + w * ce[0], 0.2f);
                }
                float att = __expf(sel_h<H>(aA, hsel) - msel) * rdensel;
                uint p = h2[(size_t)s * (FS / 2) + flane];
                __half2 hp = *(__half2*)&p;
                if (sub == 0) {
                    accx += __low2float(hp) * att;
                    accy += __high2float(hp) * att;
                }
            }
        }
        accx += __shfl_xor(accx, 32);
        accy += __shfl_xor(accy, 32);
        if (sub == 0) {
            if constexpr (FINAL) {
                if (f0 < 50) {
                    float o0 = accx + b[f0];
                    float o1 = accy + b[f0 + 1];
                    o0 = (o0 - bn_rm[f0]) * rsqrtf(bn_rv[f0] + 1e-5f) * bn_g[f0] + bn_b[f0];
                    o1 = (o1 - bn_rm[f0 + 1]) * rsqrtf(bn_rv[f0 + 1] + 1e-5f) * bn_g[f0 + 1] + bn_b[f0 + 1];
                    o0 = lrelu(o0, 0.01f);
                    o1 = lrelu(o1, 0.01f);
                    ((float2*)out)[(size_t)n * 32 + flane] = make_float2(o0, o1);
                }
            } else {
                float o0 = lrelu(accx + b[f0], 0.01f);
                float o1 = lrelu(accy + b[f0 + 1], 0.01f);
                ((float2*)out)[(size_t)n * (F / 2) + flane] = make_float2(o0, o1);
            }
        }
    }
}

// ---------------- graph pooling: segment-sum via sorted batch (binary search) ----------------
__global__ __launch_bounds__(256) void k_pool(const float* __restrict__ nodeout, const int* __restrict__ batch,
                                              float* __restrict__ gbuf) {
    int wid = threadIdx.x >> 6;
    int lane = threadIdx.x & 63;
    int g = blockIdx.x * 4 + wid;
    int lo = 0, hi = NN;
    while (lo < hi) {
        int mid = (lo + hi) >> 1;
        if (batch[mid] < g) lo = mid + 1; else hi = mid;
    }
    int s0 = lo;
    hi = NN;
    while (lo < hi) {
        int mid = (lo + hi) >> 1;
        if (batch[mid] < g + 1) lo = mid + 1; else hi = mid;
    }
    int s1 = lo;
    if (lane < 50) {
        float acc = 0.f;
        for (int n = s0; n < s1; ++n) acc += nodeout[(size_t)n * 64 + lane];
        gbuf[(size_t)g * 50 + lane] = acc;
    }
}

// ---------------- final MLP over graphs ----------------
__global__ void k_mlp(const float* __restrict__ gbuf,
                      const float* __restrict__ Wf1, const float* __restrict__ bf1,
                      const float* __restrict__ Wf2, const float* __restrict__ bf2,
                      const float* __restrict__ Wf3, const float* __restrict__ bf3,
                      float* __restrict__ out) {
    __shared__ float W1[1500], W2[600], W3[40], B1[30], B2[20], B3[2];
    int t = threadIdx.x;
    for (int i = t; i < 1500; i += 256) W1[i] = Wf1[i];
    for (int i = t; i < 600; i += 256) W2[i] = Wf2[i];
    for (int i = t; i < 40; i += 256) W3[i] = Wf3[i];
    if (t < 30) B1[t] = bf1[t];
    if (t < 20) B2[t] = bf2[t];
    if (t < 2) B3[t] = bf3[t];
    __syncthreads();
    int g = blockIdx.x * 256 + t;
    float gv[50];
#pragma unroll
    for (int i = 0; i < 50; i++) gv[i] = gbuf[(size_t)g * 50 + i];
    float h1[30];
#pragma unroll
    for (int j = 0; j < 30; j++) {
        float a = B1[j];
#pragma unroll
        for (int i = 0; i < 50; i++) a += gv[i] * W1[i * 30 + j];
        h1[j] = lrelu(a, 0.01f);
    }
    float h2[20];
#pragma unroll
    for (int j = 0; j < 20; j++) {
        float a = B2[j];
#pragma unroll
        for (int i = 0; i < 30; i++) a += h1[i] * W2[i * 20 + j];
        h2[j] = lrelu(a, 0.01f);
    }
#pragma unroll
    for (int j = 0; j < 2; j++) {
        float a = B3[j];
#pragma unroll
        for (int i = 0; i < 20; i++) a += h2[i] * W3[i * 2 + j];
        out[(size_t)g * 2 + j] = a;
    }
}

extern "C" void kernel_launch(void* const* d_in, const int* in_sizes, int n_in,
                              void* d_out, int out_size, void* d_ws, size_t ws_size,
                              hipStream_t stream) {
    const float* x = (const float*)d_in[0];
    const int* ei = (const int*)d_in[1];
    const float* ew = (const float*)d_in[2];
    const int* batch = (const int*)d_in[3];
    const float* W1 = (const float*)d_in[4];
    const float* as1 = (const float*)d_in[5];
    const float* ad1 = (const float*)d_in[6];
    const float* We1 = (const float*)d_in[7];
    const float* ae1 = (const float*)d_in[8];
    const float* b1 = (const float*)d_in[9];
    const float* W2 = (const float*)d_in[10];
    const float* as2 = (const float*)d_in[11];
    const float* ad2 = (const float*)d_in[12];
    const float* We2 = (const float*)d_in[13];
    const float* ae2 = (const float*)d_in[14];
    const float* b2 = (const float*)d_in[15];
    const float* W3 = (const float*)d_in[16];
    const float* as3 = (const float*)d_in[17];
    const float* ad3 = (const float*)d_in[18];
    const float* We3 = (const float*)d_in[19];
    const float* ae3 = (const float*)d_in[20];
    const float* b3 = (const float*)d_in[21];
    const float* W4 = (const float*)d_in[22];
    const float* as4 = (const float*)d_in[23];
    const float* ad4 = (const float*)d_in[24];
    const float* We4 = (const float*)d_in[25];
    const float* ae4 = (const float*)d_in[26];
    const float* b4 = (const float*)d_in[27];
    const float* bn_g = (const float*)d_in[28];
    const float* bn_b = (const float*)d_in[29];
    const float* bn_rm = (const float*)d_in[30];
    const float* bn_rv = (const float*)d_in[31];
    const float* Wf1 = (const float*)d_in[32];
    const float* bf1 = (const float*)d_in[33];
    const float* Wf2 = (const float*)d_in[34];
    const float* bf2 = (const float*)d_in[35];
    const float* Wf3 = (const float*)d_in[36];
    const float* bf3 = (const float*)d_in[37];
    float* out = (float*)d_out;

    const int* src = ei;
    const int* dst = ei + NE;

    // workspace layout
    char* ws = (char*)d_ws;
    float* feat = (float*)ws;   ws += (size_t)NN * 128 * 4;  // 64 MB (f32 activations / layer-4 node out)
    __half* hbuf = (__half*)ws; ws += (size_t)NN * 128 * 2;  // 32 MB (fp16 transformed h)
    float* as_buf = (float*)ws; ws += (size_t)NN * 4 * 4;
    float* ad_buf = (float*)ws; ws += (size_t)NN * 4 * 4;
    int* cnt = (int*)ws;        ws += (size_t)NN * 4;
    int* rowptr = (int*)ws;     ws += (size_t)(NN + 64) * 4;
    int* cursor = (int*)ws;     ws += (size_t)NN * 4;
    int* perm = (int*)ws;       ws += (size_t)NE * 4;
    int* part = (int*)ws;       ws += 512 * 4;
    float* gbuf = (float*)ws;   ws += (size_t)NG * 50 * 4;

    // CSR build
    hipMemsetAsync(cnt, 0, (size_t)NN * 4, stream);
    k_hist<<<NE / 256, 256, 0, stream>>>(dst, cnt);
    k_scan1<<<NN / 256, 256, 0, stream>>>(cnt, rowptr, part);
    k_scan2<<<1, 512, 0, stream>>>(part);
    k_scan3<<<NN / 256, 256, 0, stream>>>(rowptr, part, cursor);
    k_scatter<<<NE / 256, 256, 0, stream>>>(dst, cursor, perm);

    // layer 1: fin=6, H=4, C=16 (F=64)
    k_transform<6, 64, 64, 64><<<NN / 4, 256, 0, stream>>>(x, W1, hbuf);
    k_alpha<4, 16, 64><<<NN * 4 / 256, 256, 0, stream>>>(hbuf, as1, ad1, as_buf, ad_buf);
    k_aggregate<4, 16, 64, false><<<NN / 4, 256, 0, stream>>>(hbuf, as_buf, ad_buf, rowptr, perm, src, ew,
                                                              We1, ae1, b1, nullptr, nullptr, nullptr, nullptr, feat);
    // layer 2: fin=64, H=4, C=32 (F=128)
    k_transform<64, 128, 128, 128><<<NN / 2, 256, 0, stream>>>(feat, W2, hbuf);
    k_alpha<4, 32, 128><<<NN * 4 / 256, 256, 0, stream>>>(hbuf, as2, ad2, as_buf, ad_buf);
    k_aggregate<4, 32, 128, false><<<NN / 4, 256, 0, stream>>>(hbuf, as_buf, ad_buf, rowptr, perm, src, ew,
                                                               We2, ae2, b2, nullptr, nullptr, nullptr, nullptr, feat);
    // layer 3: fin=128, H=4, C=16 (F=64)
    k_transform<128, 64, 64, 64><<<NN / 4, 256, 0, stream>>>(feat, W3, hbuf);
    k_alpha<4, 16, 64><<<NN * 4 / 256, 256, 0, stream>>>(hbuf, as3, ad3, as_buf, ad_buf);
    k_aggregate<4, 16, 64, false><<<NN / 4, 256, 0, stream>>>(hbuf, as_buf, ad_buf, rowptr, perm, src, ew,
                                                              We3, ae3, b3, nullptr, nullptr, nullptr, nullptr, feat);
    // layer 4: fin=64, H=1, C=50 (F=50, padded stride 64), fused bias+BN+lrelu, per-node out
    k_transform<64, 50, 64, 64><<<NN / 4, 256, 0, stream>>>(feat, W4, hbuf);
    k_alpha<1, 50, 64><<<NN / 256, 256, 0, stream>>>(hbuf, as4, ad4, as_buf, ad_buf);
    k_aggregate<1, 50, 64, true><<<NN / 4, 256, 0, stream>>>(hbuf, as_buf, ad_buf, rowptr, perm, src, ew,
                                                             We4, ae4, b4, bn_g, bn_b, bn_rm, bn_rv, feat);
    // graph pooling (sorted batch, binary search) + final MLP
    k_pool<<<NG / 4, 256, 0, stream>>>(feat, batch, gbuf);
    k_mlp<<<NG / 256, 256, 0, stream>>>(gbuf, Wf1, bf1, Wf2, bf2, Wf3, bf3, out);
}